// Round 2
// baseline (433.669 us; speedup 1.0000x reference)
//
#include <hip/hip_runtime.h>

typedef short bf16x8 __attribute__((ext_vector_type(8)));
typedef float f32x4 __attribute__((ext_vector_type(4)));
typedef unsigned int u32x4 __attribute__((ext_vector_type(4)));

#define MFMA_16x16x32_BF16(a, b, c) __builtin_amdgcn_mfma_f32_16x16x32_bf16((a), (b), (c), 0, 0, 0)

__device__ __forceinline__ unsigned f2bf_u(float f) {
    unsigned u = __builtin_bit_cast(unsigned, f);
    unsigned r = u + 0x7FFFu + ((u >> 16) & 1u);   // RNE
    return r >> 16;                                 // low 16 bits valid
}
__device__ __forceinline__ unsigned short f2bf(float f) { return (unsigned short)f2bf_u(f); }

__device__ __forceinline__ float sigm(float x) {
    float e = __builtin_amdgcn_exp2f(-1.44269504088896f * x);
    return __builtin_amdgcn_rcpf(1.0f + e);
}
__device__ __forceinline__ float tanh_fast(float x) {
    float e = __builtin_amdgcn_exp2f(2.88539008177793f * x);
    return 1.0f - 2.0f * __builtin_amdgcn_rcpf(1.0f + e);
}

// Two waves per group of 16 batches. Wave w owns h-units 16w..16w+15.
// Lane l: batch n = l&15, q = l>>4. Lane computes h-units j = 16w + 4q + r (r=0..3).
// Per step each wave does 8 MFMAs (4 gates x {x-proj, h-recurrent}); the two
// waves exchange their bf16 h halves through double-buffered LDS (1 barrier/step).
__global__ __launch_bounds__(128) void lstm_mfma2_kernel(
    const float* __restrict__ x,     // [B,512,3]
    const float* __restrict__ W_ih,  // [128,3]
    const float* __restrict__ W_hh,  // [128,32]
    const float* __restrict__ b_ih,  // [128]
    const float* __restrict__ b_hh,  // [128]
    const float* __restrict__ W_fc,  // [32]
    const float* __restrict__ b_fc,  // [1]
    float* __restrict__ out)         // [B]
{
    const int lane = threadIdx.x & 63;
    const int w    = threadIdx.x >> 6;   // which h-half this wave owns
    const int n    = lane & 15;
    const int q    = lane >> 4;
    const int group = blockIdx.x;

    __shared__ uint2 hbuf[2][2][64];   // [buf][w][n*4+q] : 2 KB, conflict-free b64
    __shared__ float fcp[2][16];

    // ---- A fragments: 4 gate tiles (G = i,f,g,o), rows 32G + 16w + n ----
    bf16x8 A_hh[4], A_x[4];
#pragma unroll
    for (int G = 0; G < 4; ++G) {
        const int g = 32 * G + 16 * w + n;
        bf16x8 a, ax;
#pragma unroll
        for (int j = 0; j < 8; ++j) {
            const int k = 16 * (j >> 2) + 4 * q + (j & 3);
            a[j] = (short)f2bf(W_hh[g * 32 + k]);
            float axv = 0.0f;
            if (q == 0 && j < 4) {
                axv = (j < 3) ? W_ih[g * 3 + j] : (b_ih[g] + b_hh[g]);
            }
            ax[j] = (short)f2bf(axv);
        }
        A_hh[G] = a;
        A_x[G]  = ax;
    }

    const long bn = (long)group * 16 + n;
    const float* xp = x + bn * (512L * 3);

    float c[4] = {0.f, 0.f, 0.f, 0.f};
    float h[4] = {0.f, 0.f, 0.f, 0.f};
    bf16x8 Bh = {0, 0, 0, 0, 0, 0, 0, 0};

    float x0 = xp[0], x1 = xp[1], x2 = xp[2];

    for (int t = 0; t < 512; ++t) {
        // B_x: meaningful only in (q==0, j<4) slots; duplicates elsewhere hit zero A cols.
        unsigned bx01 = f2bf_u(x0) | (f2bf_u(x1) << 16);
        unsigned bx23 = f2bf_u(x2) | (0x3F80u << 16);   // bf16(1.0) pairs with bias col
        u32x4 bxv = {bx01, bx23, bx01, bx23};
        bf16x8 Bx = __builtin_bit_cast(bf16x8, bxv);

        const int tn = (t < 511) ? (t + 1) : 511;
        x0 = xp[tn * 3 + 0];
        x1 = xp[tn * 3 + 1];
        x2 = xp[tn * 3 + 2];

        f32x4 acc[4];
#pragma unroll
        for (int G = 0; G < 4; ++G) {
            f32x4 z = {0.f, 0.f, 0.f, 0.f};
            acc[G] = MFMA_16x16x32_BF16(A_x[G], Bx, z);
        }
#pragma unroll
        for (int G = 0; G < 4; ++G) {
            acc[G] = MFMA_16x16x32_BF16(A_hh[G], Bh, acc[G]);
        }

#pragma unroll
        for (int r = 0; r < 4; ++r) {
            float ig = sigm(acc[0][r]);
            float fg = sigm(acc[1][r]);
            float gg = tanh_fast(acc[2][r]);
            float og = sigm(acc[3][r]);
            c[r] = fg * c[r] + ig * gg;
            h[r] = og * tanh_fast(c[r]);
        }

        // pack own half (4 bf16), exchange through LDS
        unsigned mlo = f2bf_u(h[0]) | (f2bf_u(h[1]) << 16);
        unsigned mhi = f2bf_u(h[2]) | (f2bf_u(h[3]) << 16);
        hbuf[t & 1][w][n * 4 + q] = make_uint2(mlo, mhi);
        __syncthreads();
        uint2 oth = hbuf[t & 1][w ^ 1][n * 4 + q];

        // B-fragment: pairs (elem 2p, 2p+1); own half -> pairs 2w,2w+1; other -> 2(1-w)..
        u32x4 bh = {w ? oth.x : mlo, w ? oth.y : mhi,
                    w ? mlo : oth.x, w ? mhi : oth.y};
        Bh = __builtin_bit_cast(bf16x8, bh);
    }

    // FC + sigmoid
    float part = 0.f;
#pragma unroll
    for (int r = 0; r < 4; ++r) {
        part += W_fc[16 * w + 4 * q + r] * h[r];
    }
    part += __shfl_xor(part, 16, 64);
    part += __shfl_xor(part, 32, 64);
    if (q == 0) fcp[w][n] = part;
    __syncthreads();
    if (w == 0 && q == 0) {
        out[bn] = sigm(fcp[0][n] + fcp[1][n] + b_fc[0]);
    }
}

extern "C" void kernel_launch(void* const* d_in, const int* in_sizes, int n_in,
                              void* d_out, int out_size, void* d_ws, size_t ws_size,
                              hipStream_t stream) {
    const float* x    = (const float*)d_in[0];
    const float* W_ih = (const float*)d_in[1];
    const float* W_hh = (const float*)d_in[2];
    const float* b_ih = (const float*)d_in[3];
    const float* b_hh = (const float*)d_in[4];
    const float* W_fc = (const float*)d_in[5];
    const float* b_fc = (const float*)d_in[6];
    float* out        = (float*)d_out;

    const int n_groups = out_size / 16;   // 1024 groups, 2 waves each
    hipLaunchKernelGGL(lstm_mfma2_kernel, dim3(n_groups), dim3(128), 0, stream,
                       x, W_ih, W_hh, b_ih, b_hh, W_fc, b_fc, out);
}

// Round 4
// 332.768 us; speedup vs baseline: 1.3032x; 1.3032x over previous
//
#include <hip/hip_runtime.h>
#include <hip/hip_bf16.h>

typedef short bf16x8 __attribute__((ext_vector_type(8)));
typedef float f32x4 __attribute__((ext_vector_type(4)));
typedef unsigned int u32x4 __attribute__((ext_vector_type(4)));

#define MFMA(a, b, c) __builtin_amdgcn_mfma_f32_16x16x32_bf16((a), (b), (c), 0, 0, 0)

__device__ __forceinline__ unsigned short f2bf(float f) {
    unsigned u = __builtin_bit_cast(unsigned, f);
    unsigned r = u + 0x7FFFu + ((u >> 16) & 1u);   // RNE
    return (unsigned short)(r >> 16);
}

// pair of f32 -> packed bf16 dword (compiler emits v_cvt_pk_bf16_f32)
__device__ __forceinline__ unsigned pk_bf16(float lo, float hi) {
    __hip_bfloat162 p = __float22bfloat162_rn(make_float2(lo, hi));
    unsigned r;
    __builtin_memcpy(&r, &p, sizeof(r));
    return r;
}

__device__ __forceinline__ float sigm(float x) {
    float e = __builtin_amdgcn_exp2f(-1.44269504088896f * x);
    return __builtin_amdgcn_rcpf(1.0f + e);
}

// One wave per 16 batches (R1 structure: lane-local recurrence, no barriers).
// Lane l: batch n = l&15, q = l>>4; owns h-units {4q+r, 16+4q+r}, r=0..3.
// Weights pre-scaled: i,f,o gate rows by -log2(e); g rows by +2*log2(e).
// Cell state kept in scaled domain c' = 2*log2(e)*c.
__global__ __launch_bounds__(256, 1) void lstm_mfma3_kernel(
    const float* __restrict__ x,     // [B,512,3]
    const float* __restrict__ W_ih,  // [128,3]
    const float* __restrict__ W_hh,  // [128,32]
    const float* __restrict__ b_ih,  // [128]
    const float* __restrict__ b_hh,  // [128]
    const float* __restrict__ W_fc,  // [32]
    const float* __restrict__ b_fc,  // [1]
    float* __restrict__ out,         // [B]
    int n_groups)
{
    const int lane  = threadIdx.x & 63;
    const int wid   = threadIdx.x >> 6;
    const int group = blockIdx.x * 4 + wid;
    if (group >= n_groups) return;

    const int n = lane & 15;
    const int q = lane >> 4;

    const float NL2E  = -1.4426950408889634f;  // -log2(e)
    const float P2L2E =  2.8853900817779268f;  // +2*log2(e)

    // tiles: (0,1)=i, (2,3)=f, (4,5)=g, (6,7)=o ; even=units 0..15, odd=16..31
    bf16x8 A_hh[8], A_x[8];
#pragma unroll
    for (int t = 0; t < 8; ++t) {
        const int g = 16 * t + n;
        const float s = (t == 4 || t == 5) ? P2L2E : NL2E;
        bf16x8 a, ax;
#pragma unroll
        for (int j = 0; j < 8; ++j) {
            const int k = 16 * (j >> 2) + 4 * q + (j & 3);
            a[j] = (short)f2bf(s * W_hh[g * 32 + k]);
            float axv = 0.0f;
            if (q == 0 && j < 4) {
                axv = (j < 3) ? s * W_ih[g * 3 + j] : s * (b_ih[g] + b_hh[g]);
            }
            ax[j] = (short)f2bf(axv);
        }
        A_hh[t] = a;
        A_x[t]  = ax;
    }

    const long bn = (long)group * 16 + n;
    const float4* xv = (const float4*)(x + bn * (512L * 3));  // 384 float4 per batch

    // state: c' (scaled), h (f32); [0..3]=lo units 4q+r, [4..7]=hi units 16+4q+r
    float cs[8] = {0.f, 0.f, 0.f, 0.f, 0.f, 0.f, 0.f, 0.f};
    float h[8]  = {0.f, 0.f, 0.f, 0.f, 0.f, 0.f, 0.f, 0.f};
    bf16x8 Bh = {0, 0, 0, 0, 0, 0, 0, 0};

    // x window for steps 0..3
    float4 xa = xv[0], xb = xv[1], xc = xv[2];

#define STEP(X0, X1, X2)                                                        \
    do {                                                                        \
        unsigned bx01 = pk_bf16((X0), (X1));                                    \
        unsigned bx23 = pk_bf16((X2), 1.0f);                                    \
        u32x4 bxv = {bx01, bx23, bx01, bx23};                                   \
        bf16x8 Bx = __builtin_bit_cast(bf16x8, bxv);                            \
        f32x4 acc[8];                                                           \
        _Pragma("unroll")                                                       \
        for (int tt = 0; tt < 8; ++tt) {                                        \
            f32x4 z = {0.f, 0.f, 0.f, 0.f};                                     \
            acc[tt] = MFMA(A_x[tt], Bx, z);                                     \
        }                                                                       \
        _Pragma("unroll")                                                       \
        for (int tt = 0; tt < 8; ++tt) acc[tt] = MFMA(A_hh[tt], Bh, acc[tt]);   \
        _Pragma("unroll")                                                       \
        for (int r = 0; r < 4; ++r) {                                           \
            float ei0 = __builtin_amdgcn_exp2f(acc[0][r]);                      \
            float ef0 = __builtin_amdgcn_exp2f(acc[2][r]);                      \
            float eg0 = __builtin_amdgcn_exp2f(acc[4][r]);                      \
            float eo0 = __builtin_amdgcn_exp2f(acc[6][r]);                      \
            float ei1 = __builtin_amdgcn_exp2f(acc[1][r]);                      \
            float ef1 = __builtin_amdgcn_exp2f(acc[3][r]);                      \
            float eg1 = __builtin_amdgcn_exp2f(acc[5][r]);                      \
            float eo1 = __builtin_amdgcn_exp2f(acc[7][r]);                      \
            float ig0 = __builtin_amdgcn_rcpf(1.0f + ei0);                      \
            float fg0 = __builtin_amdgcn_rcpf(1.0f + ef0);                      \
            float rg0 = __builtin_amdgcn_rcpf(1.0f + eg0);                      \
            float og0 = __builtin_amdgcn_rcpf(1.0f + eo0);                      \
            float ig1 = __builtin_amdgcn_rcpf(1.0f + ei1);                      \
            float fg1 = __builtin_amdgcn_rcpf(1.0f + ef1);                      \
            float rg1 = __builtin_amdgcn_rcpf(1.0f + eg1);                      \
            float og1 = __builtin_amdgcn_rcpf(1.0f + eo1);                      \
            float gp0 = fmaf(-5.7707801635558536f, rg0, P2L2E);                 \
            float gp1 = fmaf(-5.7707801635558536f, rg1, P2L2E);                 \
            cs[r]     = fmaf(fg0, cs[r],     ig0 * gp0);                        \
            cs[4 + r] = fmaf(fg1, cs[4 + r], ig1 * gp1);                        \
            float ec0 = __builtin_amdgcn_exp2f(cs[r]);                          \
            float ec1 = __builtin_amdgcn_exp2f(cs[4 + r]);                      \
            float tc0 = fmaf(-2.0f, __builtin_amdgcn_rcpf(1.0f + ec0), 1.0f);   \
            float tc1 = fmaf(-2.0f, __builtin_amdgcn_rcpf(1.0f + ec1), 1.0f);   \
            h[r]      = og0 * tc0;                                              \
            h[4 + r]  = og1 * tc1;                                              \
        }                                                                       \
        u32x4 bhv = {pk_bf16(h[0], h[1]), pk_bf16(h[2], h[3]),                  \
                     pk_bf16(h[4], h[5]), pk_bf16(h[6], h[7])};                 \
        Bh = __builtin_bit_cast(bf16x8, bhv);                                   \
    } while (0)

    for (int w4 = 0; w4 < 128; ++w4) {
        // prefetch next 4-step x window (one full window of latency hiding)
        const int nw = (w4 < 127) ? (w4 + 1) : 127;
        float4 na = xv[3 * nw + 0];
        float4 nb = xv[3 * nw + 1];
        float4 nc = xv[3 * nw + 2];

        STEP(xa.x, xa.y, xa.z);
        STEP(xa.w, xb.x, xb.y);
        STEP(xb.z, xb.w, xc.x);
        STEP(xc.y, xc.z, xc.w);

        xa = na; xb = nb; xc = nc;
    }
#undef STEP

    // FC + sigmoid
    float part = 0.f;
#pragma unroll
    for (int r = 0; r < 4; ++r) {
        part += W_fc[4 * q + r] * h[r];
        part += W_fc[16 + 4 * q + r] * h[4 + r];
    }
    part += __shfl_xor(part, 16, 64);
    part += __shfl_xor(part, 32, 64);
    if (q == 0) {
        out[bn] = sigm(part + b_fc[0]);
    }
}

extern "C" void kernel_launch(void* const* d_in, const int* in_sizes, int n_in,
                              void* d_out, int out_size, void* d_ws, size_t ws_size,
                              hipStream_t stream) {
    const float* x    = (const float*)d_in[0];
    const float* W_ih = (const float*)d_in[1];
    const float* W_hh = (const float*)d_in[2];
    const float* b_ih = (const float*)d_in[3];
    const float* b_hh = (const float*)d_in[4];
    const float* W_fc = (const float*)d_in[5];
    const float* b_fc = (const float*)d_in[6];
    float* out        = (float*)d_out;

    const int n_groups = out_size / 16;      // 1024 waves
    const int n_blocks = (n_groups + 3) / 4; // 4 waves (256 threads) per block

    hipLaunchKernelGGL(lstm_mfma3_kernel, dim3(n_blocks), dim3(256), 0, stream,
                       x, W_ih, W_hh, b_ih, b_hh, W_fc, b_fc, out, n_groups);
}

// Round 5
// 317.773 us; speedup vs baseline: 1.3647x; 1.0472x over previous
//
#include <hip/hip_runtime.h>
#include <hip/hip_bf16.h>

typedef short bf16x8 __attribute__((ext_vector_type(8)));
typedef float f32x4 __attribute__((ext_vector_type(4)));
typedef unsigned int u32x4 __attribute__((ext_vector_type(4)));

#define MFMA(a, b, c) __builtin_amdgcn_mfma_f32_16x16x32_bf16((a), (b), (c), 0, 0, 0)

__device__ __forceinline__ unsigned short f2bf(float f) {
    unsigned u = __builtin_bit_cast(unsigned, f);
    unsigned r = u + 0x7FFFu + ((u >> 16) & 1u);   // RNE
    return (unsigned short)(r >> 16);
}

// pair of f32 -> packed bf16 dword (v_cvt_pk_bf16_f32)
__device__ __forceinline__ unsigned pk_bf16(float lo, float hi) {
    __hip_bfloat162 p = __float22bfloat162_rn(make_float2(lo, hi));
    unsigned r;
    __builtin_memcpy(&r, &p, sizeof(r));
    return r;
}

__device__ __forceinline__ float sigm(float x) {
    float e = __builtin_amdgcn_exp2f(-1.44269504088896f * x);
    return __builtin_amdgcn_rcpf(1.0f + e);
}

// One wave per 16 batches; lane-local recurrence, no barriers.
// Lane l: batch n = l&15, q = l>>4; owns h-units {4q+r, 16+4q+r}, r=0..3.
// Weights pre-scaled: i,f,o rows by -log2(e); g rows by +2*log2(e).
// Cell state kept scaled: c' = 2*log2(e)*c.
// Loop-carried accx[8] = x-projection MFMAs for the NEXT step (software pipeline).
__global__ __launch_bounds__(256, 1) void lstm_mfma5_kernel(
    const float* __restrict__ x,     // [B,512,3]
    const float* __restrict__ W_ih,  // [128,3]
    const float* __restrict__ W_hh,  // [128,32]
    const float* __restrict__ b_ih,  // [128]
    const float* __restrict__ b_hh,  // [128]
    const float* __restrict__ W_fc,  // [32]
    const float* __restrict__ b_fc,  // [1]
    float* __restrict__ out,         // [B]
    int n_groups)
{
    const int lane  = threadIdx.x & 63;
    const int wid   = threadIdx.x >> 6;
    const int group = blockIdx.x * 4 + wid;
    if (group >= n_groups) return;

    const int n = lane & 15;
    const int q = lane >> 4;

    const float NL2E  = -1.4426950408889634f;  // -log2(e)
    const float P2L2E =  2.8853900817779268f;  // +2*log2(e)

    // tiles: (0,1)=i, (2,3)=f, (4,5)=g, (6,7)=o ; even=units 0..15, odd=16..31
    bf16x8 A_hh[8], A_x[8];
#pragma unroll
    for (int t = 0; t < 8; ++t) {
        const int g = 16 * t + n;
        const float s = (t == 4 || t == 5) ? P2L2E : NL2E;
        bf16x8 a, ax;
#pragma unroll
        for (int j = 0; j < 8; ++j) {
            const int k = 16 * (j >> 2) + 4 * q + (j & 3);
            a[j] = (short)f2bf(s * W_hh[g * 32 + k]);
            float axv = 0.0f;
            if (q == 0 && j < 4) {
                axv = (j < 3) ? s * W_ih[g * 3 + j] : s * (b_ih[g] + b_hh[g]);
            }
            ax[j] = (short)f2bf(axv);
        }
        A_hh[t] = a;
        A_x[t]  = ax;
    }

    const long bn = (long)group * 16 + n;
    const float4* xv = (const float4*)(x + bn * (512L * 3));  // 384 float4/batch

    float cs[8] = {0.f, 0.f, 0.f, 0.f, 0.f, 0.f, 0.f, 0.f};
    float h[8]  = {0.f, 0.f, 0.f, 0.f, 0.f, 0.f, 0.f, 0.f};
    bf16x8 Bh = {0, 0, 0, 0, 0, 0, 0, 0};

    float4 xa = xv[0], xb = xv[1], xc = xv[2];

    // prologue: x-projection for step 0 (x(0) = xa.x,y,z)
    f32x4 accx[8];
    {
        unsigned bx01 = pk_bf16(xa.x, xa.y);
        unsigned bx23 = pk_bf16(xa.z, 1.0f);
        u32x4 bxv = {bx01, bx23, bx01, bx23};
        bf16x8 Bx = __builtin_bit_cast(bf16x8, bxv);
#pragma unroll
        for (int tt = 0; tt < 8; ++tt) {
            f32x4 z = {0.f, 0.f, 0.f, 0.f};
            accx[tt] = MFMA(A_x[tt], Bx, z);
        }
    }

// STEP consumes carried accx (this step's x-proj) and x(t+1) components
// (XN0..XN2) to prefetch next step's accx while the cell phase runs.
#define STEP(XN0, XN1, XN2)                                                     \
    do {                                                                        \
        f32x4 acc[8];                                                           \
        _Pragma("unroll")                                                       \
        for (int tt = 0; tt < 8; ++tt) acc[tt] = MFMA(A_hh[tt], Bh, accx[tt]);  \
        unsigned bx01 = pk_bf16((XN0), (XN1));                                  \
        unsigned bx23 = pk_bf16((XN2), 1.0f);                                   \
        u32x4 bxv = {bx01, bx23, bx01, bx23};                                   \
        bf16x8 Bx = __builtin_bit_cast(bf16x8, bxv);                            \
        _Pragma("unroll")                                                       \
        for (int tt = 0; tt < 8; ++tt) {                                        \
            f32x4 z = {0.f, 0.f, 0.f, 0.f};                                     \
            accx[tt] = MFMA(A_x[tt], Bx, z);                                    \
        }                                                                       \
        _Pragma("unroll")                                                       \
        for (int r = 0; r < 4; ++r) {                                           \
            float ei0 = __builtin_amdgcn_exp2f(acc[0][r]);                      \
            float ef0 = __builtin_amdgcn_exp2f(acc[2][r]);                      \
            float eg0 = __builtin_amdgcn_exp2f(acc[4][r]);                      \
            float eo0 = __builtin_amdgcn_exp2f(acc[6][r]);                      \
            float ei1 = __builtin_amdgcn_exp2f(acc[1][r]);                      \
            float ef1 = __builtin_amdgcn_exp2f(acc[3][r]);                      \
            float eg1 = __builtin_amdgcn_exp2f(acc[5][r]);                      \
            float eo1 = __builtin_amdgcn_exp2f(acc[7][r]);                      \
            float a0 = 1.0f + ei0, b0 = 1.0f + ef0;                             \
            float c0 = 1.0f + eg0, d0 = 1.0f + eo0;                             \
            float a1 = 1.0f + ei1, b1 = 1.0f + ef1;                             \
            float c1 = 1.0f + eg1, d1 = 1.0f + eo1;                             \
            float rp0 = __builtin_amdgcn_rcpf(a0 * b0);                         \
            float rq0 = __builtin_amdgcn_rcpf(c0 * d0);                         \
            float rp1 = __builtin_amdgcn_rcpf(a1 * b1);                         \
            float rq1 = __builtin_amdgcn_rcpf(c1 * d1);                         \
            float ig0 = b0 * rp0, fg0 = a0 * rp0;                               \
            float rg0 = d0 * rq0, og0 = c0 * rq0;                               \
            float ig1 = b1 * rp1, fg1 = a1 * rp1;                               \
            float rg1 = d1 * rq1, og1 = c1 * rq1;                               \
            float gp0 = fmaf(-5.7707801635558536f, rg0, P2L2E);                 \
            float gp1 = fmaf(-5.7707801635558536f, rg1, P2L2E);                 \
            cs[r]     = fmaf(fg0, cs[r],     ig0 * gp0);                        \
            cs[4 + r] = fmaf(fg1, cs[4 + r], ig1 * gp1);                        \
            float ec0 = __builtin_amdgcn_exp2f(cs[r]);                          \
            float ec1 = __builtin_amdgcn_exp2f(cs[4 + r]);                      \
            float tc0 = fmaf(-2.0f, __builtin_amdgcn_rcpf(1.0f + ec0), 1.0f);   \
            float tc1 = fmaf(-2.0f, __builtin_amdgcn_rcpf(1.0f + ec1), 1.0f);   \
            h[r]      = og0 * tc0;                                              \
            h[4 + r]  = og1 * tc1;                                              \
        }                                                                       \
        u32x4 bhv = {pk_bf16(h[0], h[1]), pk_bf16(h[2], h[3]),                  \
                     pk_bf16(h[4], h[5]), pk_bf16(h[6], h[7])};                 \
        Bh = __builtin_bit_cast(bf16x8, bhv);                                   \
    } while (0)

    for (int w4 = 0; w4 < 128; ++w4) {
        const int nw = (w4 < 127) ? (w4 + 1) : 127;
        float4 na = xv[3 * nw + 0];
        float4 nb = xv[3 * nw + 1];
        float4 nc = xv[3 * nw + 2];

        // steps 4*w4 .. 4*w4+3; each prefetches x(t+1)
        STEP(xa.w, xb.x, xb.y);
        STEP(xb.z, xb.w, xc.x);
        STEP(xc.y, xc.z, xc.w);
        STEP(na.x, na.y, na.z);   // last step's prefetch crosses into next window

        xa = na; xb = nb; xc = nc;
    }
#undef STEP

    // FC + sigmoid
    float part = 0.f;
#pragma unroll
    for (int r = 0; r < 4; ++r) {
        part += W_fc[4 * q + r] * h[r];
        part += W_fc[16 + 4 * q + r] * h[4 + r];
    }
    part += __shfl_xor(part, 16, 64);
    part += __shfl_xor(part, 32, 64);
    if (q == 0) {
        out[bn] = sigm(part + b_fc[0]);
    }
}

extern "C" void kernel_launch(void* const* d_in, const int* in_sizes, int n_in,
                              void* d_out, int out_size, void* d_ws, size_t ws_size,
                              hipStream_t stream) {
    const float* x    = (const float*)d_in[0];
    const float* W_ih = (const float*)d_in[1];
    const float* W_hh = (const float*)d_in[2];
    const float* b_ih = (const float*)d_in[3];
    const float* b_hh = (const float*)d_in[4];
    const float* W_fc = (const float*)d_in[5];
    const float* b_fc = (const float*)d_in[6];
    float* out        = (float*)d_out;

    const int n_groups = out_size / 16;      // 1024 waves
    const int n_blocks = (n_groups + 3) / 4; // 4 waves (256 threads) per block

    hipLaunchKernelGGL(lstm_mfma5_kernel, dim3(n_blocks), dim3(256), 0, stream,
                       x, W_ih, W_hh, b_ih, b_hh, W_fc, b_fc, out, n_groups);
}